// Round 2
// baseline (44.488 us; speedup 1.0000x reference)
//
#include <hip/hip_runtime.h>

#define R 128
#define C 256
#define P 7
#define HW 64

__global__ __launch_bounds__(256) void
roi_pool_kernel(const float* __restrict__ x,
                const int* __restrict__ rois,
                float* __restrict__ out) {
    const int lane = threadIdx.x & 63;
    const int wid  = threadIdx.x >> 6;
    const int gw   = blockIdx.x * 4 + wid;   // global wave id = r*C + c
    const int c = gw & (C - 1);
    const int r = gw >> 8;                   // gw / 256

    // ROI params are wave-uniform (r depends only on blockIdx) -> s_load
    const int rx = rois[r * 4 + 0];
    const int ry = rois[r * 4 + 1];
    const int rw = rois[r * 4 + 2];
    const int rh = rois[r * 4 + 3];

    const float rlx = (float)rw / 7.0f;
    const float rly = (float)rh / 7.0f;
    const int kw = (int)rlx;                 // floor(rl), rl >= 1
    const int kh = (int)rly;

    // Per-lane horizontal bin start (meaningful for lane < 7).
    // Match JAX exactly: floor(coord + i*rl) with separate rn mul + rn add.
    const int sxl = (int)floorf(__fadd_rn((float)rx, __fmul_rn((float)lane, rlx)));

    const float* xc = x + (size_t)c * (HW * HW);
    float* outrc = out + (size_t)(r * C + c) * (P * P);

    const float NEG = -3.402823466e38f;

    #pragma unroll
    for (int py = 0; py < P; ++py) {
        const int sy = (int)floorf(__fadd_rn((float)ry, __fmul_rn((float)py, rly)));
        // vertical max over this py-band, one column per lane (coalesced)
        float vm = NEG;
        const float* p = xc + sy * HW + lane;
        for (int iy = 0; iy < kh; ++iy) {
            vm = fmaxf(vm, p[(size_t)iy * HW]);
        }
        // horizontal max over [sxl, sxl+kw) via cross-lane pulls
        float o = NEG;
        for (int j = 0; j < kw; ++j) {
            o = fmaxf(o, __shfl(vm, sxl + j, 64));
        }
        if (lane < P) outrc[py * P + lane] = o;
    }
}

extern "C" void kernel_launch(void* const* d_in, const int* in_sizes, int n_in,
                              void* d_out, int out_size, void* d_ws, size_t ws_size,
                              hipStream_t stream) {
    const float* x = (const float*)d_in[0];
    const int* rois = (const int*)d_in[1];
    float* out = (float*)d_out;

    // one wave per (r,c): R*C = 32768 waves, 4 waves per 256-thread block
    const int grid = (R * C) / 4;  // 8192
    roi_pool_kernel<<<grid, 256, 0, stream>>>(x, rois, out);
}

// Round 3
// 30.680 us; speedup vs baseline: 1.4501x; 1.4501x over previous
//
#include <hip/hip_runtime.h>

#define R 128
#define C 256
#define P 7
#define HW 64

__global__ __launch_bounds__(256) void
roi_pool_kernel(const float* __restrict__ x,
                const int* __restrict__ rois,
                float* __restrict__ out) {
    const int lane = threadIdx.x & 63;
    // Force wave id scalar so r, c, rois, kh, kw, sy all land in SGPRs.
    const int wid  = __builtin_amdgcn_readfirstlane(threadIdx.x >> 6);
    const int gw   = blockIdx.x * 4 + wid;   // global wave id = r*C + c
    const int c = gw & (C - 1);
    const int r = gw >> 8;

    const int rx = rois[r * 4 + 0];          // scalar loads
    const int ry = rois[r * 4 + 1];
    const int rw = rois[r * 4 + 2];
    const int rh = rois[r * 4 + 3];

    // Match JAX exactly: f32 divide, floor(coord + i*rl) with rn mul + rn add.
    const float rlx = (float)rw / 7.0f;
    const float rly = (float)rh / 7.0f;
    const int kw = __builtin_amdgcn_readfirstlane((int)rlx);  // floor, >=1
    const int kh = __builtin_amdgcn_readfirstlane((int)rly);

    // Per-lane horizontal bin start (lane plays px for lanes 0..6).
    const int sxl = (int)floorf(__fadd_rn((float)rx, __fmul_rn((float)lane, rlx)));
    const int sxrel = sxl - rx;              // column relative to rx

    const float* xc = x + (size_t)c * (HW * HW);
    float* outrc = out + (size_t)(r * C + c) * (P * P);
    const float NEG = -3.402823466e38f;
    const bool active = lane < rw;           // needed cols = [rx, rx+rw)

    #pragma unroll
    for (int py = 0; py < P; ++py) {
        const int sy = __builtin_amdgcn_readfirstlane(
            (int)floorf(__fadd_rn((float)ry, __fmul_rn((float)py, rly))));

        // Vertical max over this band; lane = column rx+lane (coalesced).
        float vm = NEG;
        if (active) {
            const float* p = xc + sy * HW + rx + lane;
            float v[8];
            #pragma unroll
            for (int j = 0; j < 8; ++j)
                if (j < kh) v[j] = p[j * HW];     // uniform branch; loads batch
            #pragma unroll
            for (int j = 0; j < 8; ++j)
                if (j < kh) vm = fmaxf(vm, v[j]);
        }

        // Sliding-window max of width kw across lanes (log-time doubling).
        float w1 = vm, w2 = vm, w4 = vm;
        if (kw >= 2) w2 = fmaxf(w1, __shfl(w1, lane + 1, 64));
        if (kw >= 4) w4 = fmaxf(w2, __shfl(w2, lane + 2, 64));
        float wm; int m;
        if (kw >= 8)      { wm = fmaxf(w4, __shfl(w4, lane + 4, 64)); m = 8; }
        else if (kw >= 4) { wm = w4; m = 4; }
        else if (kw >= 2) { wm = w2; m = 2; }
        else              { wm = w1; m = 1; }
        const int rem = kw - m;              // uniform, in [0, m-1]
        float wk = wm;
        if (rem) wk = fmaxf(wm, __shfl(wm, lane + rem, 64));

        // Gather bin px=lane's window value and store (7 lanes).
        float o = __shfl(wk, sxrel, 64);
        if (lane < P) outrc[py * P + lane] = o;
    }
}

extern "C" void kernel_launch(void* const* d_in, const int* in_sizes, int n_in,
                              void* d_out, int out_size, void* d_ws, size_t ws_size,
                              hipStream_t stream) {
    const float* x = (const float*)d_in[0];
    const int* rois = (const int*)d_in[1];
    float* out = (float*)d_out;

    const int grid = (R * C) / 4;  // one wave per (r,c), 4 waves/block
    roi_pool_kernel<<<grid, 256, 0, stream>>>(x, rois, out);
}

// Round 4
// 24.369 us; speedup vs baseline: 1.8256x; 1.2590x over previous
//
#include <hip/hip_runtime.h>

#define R 128
#define C 256
#define P 7
#define HW 64
#define LSTRIDE 65   // 7 rows of 65 floats per wave slab (padded vs 64: spreads banks)

__global__ __launch_bounds__(256) void
roi_pool_kernel(const float* __restrict__ x,
                const int* __restrict__ rois,
                float* __restrict__ out) {
    const int lane = threadIdx.x & 63;
    const int wid  = __builtin_amdgcn_readfirstlane(threadIdx.x >> 6);
    const int gw   = blockIdx.x * 4 + wid;   // global wave id = r*C + c
    const int c = gw & (C - 1);
    const int r = gw >> 8;

    __shared__ float vmbuf[4][P * LSTRIDE];
    float* slab = vmbuf[wid];

    const int rx = rois[r * 4 + 0];          // scalar loads (r is SGPR)
    const int ry = rois[r * 4 + 1];
    const int rw = rois[r * 4 + 2];
    const int rh = rois[r * 4 + 3];

    // Match JAX: f32 rn divide; floor(coord + i*rl) with separate rn mul+add.
    const float rlx = (float)rw / 7.0f;
    const float rly = (float)rh / 7.0f;
    const int kw = __builtin_amdgcn_readfirstlane((int)rlx);  // floor(rl) >= 1
    const int kh = __builtin_amdgcn_readfirstlane((int)rly);

    // Vector-parallel precompute of band starts: lane plays py for lanes 0..6.
    const int syv = (int)floorf(__fadd_rn((float)ry, __fmul_rn((float)lane, rly)));

    const float* xc = x + (size_t)c * (HW * HW);
    const float NEG = -3.402823466e38f;

    // ---- Phase 1: vertical band maxes, lane = column (fully coalesced) ----
    #pragma unroll
    for (int py = 0; py < P; ++py) {
        const int sy = __builtin_amdgcn_readlane(syv, py);  // SGPR
        const float* p = xc + sy * HW + lane;
        float v[8];
        #pragma unroll
        for (int j = 0; j < 8; ++j)
            if (j < kh) v[j] = p[j * HW];    // uniform branch; loads batch
        float vm = NEG;
        #pragma unroll
        for (int j = 0; j < 8; ++j)
            if (j < kh) vm = fmaxf(vm, v[j]);
        slab[py * LSTRIDE + lane] = vm;      // ds_write, conflict-free
    }

    // ---- Phase 2: one lane per output bin; independent ds_reads ----
    if (lane < P * P) {
        const int py = lane / 7;             // magic-mul
        const int px = lane - py * 7;
        const int sx = (int)floorf(__fadd_rn((float)rx, __fmul_rn((float)px, rlx)));
        const float* w = slab + py * LSTRIDE + sx;
        float v[8];
        #pragma unroll
        for (int j = 0; j < 8; ++j)
            if (j < kw) v[j] = w[j];         // ds_read batch, imm offsets
        float m = NEG;
        #pragma unroll
        for (int j = 0; j < 8; ++j)
            if (j < kw) m = fmaxf(m, v[j]);
        out[(size_t)(r * C + c) * (P * P) + lane] = m;  // 49 consecutive floats
    }
}

extern "C" void kernel_launch(void* const* d_in, const int* in_sizes, int n_in,
                              void* d_out, int out_size, void* d_ws, size_t ws_size,
                              hipStream_t stream) {
    const float* x = (const float*)d_in[0];
    const int* rois = (const int*)d_in[1];
    float* out = (float*)d_out;

    const int grid = (R * C) / 4;  // one wave per (r,c), 4 waves/block
    roi_pool_kernel<<<grid, 256, 0, stream>>>(x, rois, out);
}